// Round 7
// baseline (3047.336 us; speedup 1.0000x reference)
//
#include <hip/hip_runtime.h>
#include <math.h>

#define NEG_INF (-1e9f)
#define WSYNC() asm volatile("s_waitcnt lgkmcnt(0)" ::: "memory")
// row->bank-group swizzle: injects row bits 0..5 into float4-chunk low bits.
#define SW(n) ((((n) ^ ((n) >> 3))) & 7)

// ---------------------------------------------------------------------------
// pre_kernel: builds into ws
//   ws[0 .. 16383]   : Wc[e][d] = (1/sqrt(128)) * sum_j W_node[e,256+j]*W_out[d,j]
//   ws[16384..16511] : qp[d]    = sum_i W_placeholder[i]*W_step[i,d]
// ---------------------------------------------------------------------------
__global__ __launch_bounds__(128) void pre_kernel(
    const float* __restrict__ W_node, const float* __restrict__ W_out,
    const float* __restrict__ W_step, const float* __restrict__ W_ph,
    float* __restrict__ ws) {
  const int bi = blockIdx.x;
  const int tid = threadIdx.x;
  if (bi < 64) {
    __shared__ float woT[64][133];
    float acc0 = 0.f, acc1 = 0.f;
    const int e0 = bi * 2, e1 = e0 + 1;
    for (int ch = 0; ch < 2; ++ch) {
      const int j0 = ch * 64;
      for (int it = 0; it < 64; ++it) {
        int idx = tid + it * 128;
        int jj = idx & 63, ds = idx >> 6;
        woT[jj][ds] = W_out[ds * 128 + j0 + jj];
      }
      __syncthreads();
      for (int jj = 0; jj < 64; ++jj) {
        int j = j0 + jj;
        float a0 = W_node[e0 * 384 + 256 + j];
        float a1 = W_node[e1 * 384 + 256 + j];
        float bb = woT[jj][tid];
        acc0 = fmaf(a0, bb, acc0);
        acc1 = fmaf(a1, bb, acc1);
      }
      __syncthreads();
    }
    const float rs = 0.08838834764831845f;  // 1/sqrt(128)
    ws[e0 * 128 + tid] = acc0 * rs;
    ws[e1 * 128 + tid] = acc1 * rs;
  } else {
    float acc = 0.f;
    for (int i = 0; i < 256; ++i) acc = fmaf(W_ph[i], W_step[i * 128 + tid], acc);
    ws[16384 + tid] = acc;
  }
}

// ---------------------------------------------------------------------------
// decode_kernel: one block (512 thr = 8 waves) per batch row.
// wave h = head h; lane l owns rows {l, l+50} (l<50 active).
//
// The 512-thread VGPR budget is hard-capped at 128 (rounds 3-6: attributes
// ignored, VGPR_Count==128, ~280 MB/dispatch spill writes). Fix: fit under it.
// lk' is per-lane CONSTANT across all 100 steps -> lives in LDS (sTab), not
// registers. sTab holds staged emb during init, then is overwritten with lk'
// (built from global emb after a barrier; each thread writes/reads only its
// own (row, col-slice), so post-write visibility needs only lgkmcnt).
// Loop-live regs: gk(32)+gvt(25)+state ~65 + transients -> fits 128, no spill.
// Swizzle chunk ^= (n ^ (n>>3)) & 7 (old n&7 left 7-way aliasing among lanes
// l, l+8, ...). One __syncthreads per decode step.
// ---------------------------------------------------------------------------
__global__ __launch_bounds__(512) void decode_kernel(
    const float* __restrict__ emb,      // [2048][100][128]
    const float* __restrict__ W_node,   // [128][384]
    const float* __restrict__ W_fixed,  // [128][128]
    const float* __restrict__ W_step,   // [256][128]
    const float* __restrict__ ws,       // Wc + qp
    float* __restrict__ out_logp,       // [2048][100][100]
    float* __restrict__ out_pi) {       // [2048][100] (as float)
  const int b = blockIdx.x;
  const int tid = threadIdx.x;
  const int h = tid >> 6;       // wave == head
  const int l = tid & 63;       // lane
  const int dp = l & 15;        // d' within head slice
  const int qg = l >> 4;        // row-quarter group 0..3
  const bool act = (l < 50);
  const int r0 = act ? l : 0;
  const int r1 = act ? l + 50 : 0;
  const int qq0 = (l < 25) ? 0 : 1;   // attn quarter of r0
  const int ii0 = l - qq0 * 25;       // index within quarter
  const int sw0 = SW(r0);
  const int sw1 = SW(r1);

  __shared__ __align__(16) float sTab[100 * 128];  // 51200 B: emb -> lk' table
  __shared__ __align__(16) float sE[8][100][16];   // 51200 B: ctx(+F)+0.25*E
  __shared__ __align__(16) float pool[3200];       // 12800 B multi-use
  __shared__ float smean[128];
  __shared__ __align__(16) float sbase[8][16];

  const float* embB = emb + (size_t)b * 12800;
  const float4* embB4 = (const float4*)embB;
  float* sTabf = sTab;
  float4* sTab4 = (float4*)sTab;

  // ---- stage emb into LDS, swizzled: phys_chunk = c ^ SW(n) ----
  for (int it = 0; it < 7; ++it) {
    int qi = tid + it * 512;
    if (qi < 3200) {
      int n = qi >> 5, c = qi & 31;
      sTab4[n * 32 + (c ^ SW(n))] = embB4[qi];
    }
  }
  __syncthreads();

  // ---- graph mean (pool as scratch) ----
  {
    int d = tid & 127, q2 = tid >> 7;
    int ch = d >> 2, cl = d & 3;
    float p = 0.f;
    for (int n = q2 * 25; n < q2 * 25 + 25; ++n)
      p += sTabf[n * 128 + ((ch ^ SW(n)) << 2) + cl];
    pool[q2 * 128 + d] = p;
  }
  __syncthreads();
  if (tid < 128)
    smean[tid] = (pool[tid] + pool[128 + tid] + pool[256 + tid] + pool[384 + tid]) * 0.01f;
  __syncthreads();

  // ---- ctx[16] = 0.25 * (mean @ W_fixed) head-slice, replicated per lane ----
  float ctx[16];
  {
    float a = 0.f;
    for (int i = 0; i < 32; ++i) {
      int e = qg * 32 + i;
      a = fmaf(smean[e], W_fixed[e * 128 + h * 16 + dp], a);
    }
    a += __shfl_xor(a, 16);
    a += __shfl_xor(a, 32);
    if (l < 16) sbase[h][l] = 0.25f * a;
    WSYNC();
#pragma unroll
    for (int jj = 0; jj < 4; ++jj) {
      float4 v = *(const float4*)&sbase[h][jj * 4];
      ctx[jj * 4 + 0] = v.x; ctx[jj * 4 + 1] = v.y;
      ctx[jj * 4 + 2] = v.z; ctx[jj * 4 + 3] = v.w;
    }
  }

  // ================= Pass A: gv rows -> transpose -> gvt[25] =================
  float gvt[25];
  {
    float gv0[16], gv1[16];
#pragma unroll
    for (int j = 0; j < 16; ++j) gv0[j] = gv1[j] = 0.f;
#pragma unroll 2
    for (int e4 = 0; e4 < 32; ++e4) {
      float4 a0 = sTab4[r0 * 32 + (e4 ^ sw0)];
      float4 a1 = sTab4[r1 * 32 + (e4 ^ sw1)];
      float em0[4] = {a0.x, a0.y, a0.z, a0.w};
      float em1[4] = {a1.x, a1.y, a1.z, a1.w};
#pragma unroll
      for (int eo = 0; eo < 4; ++eo) {
        const int e = e4 * 4 + eo;
        const float ev0 = em0[eo], ev1 = em1[eo];
        const float* wv = &W_node[e * 384 + 128 + h * 16];
#pragma unroll
        for (int j = 0; j < 16; ++j) {
          float wvj = wv[j];
          gv0[j] = fmaf(ev0, wvj, gv0[j]);
          gv1[j] = fmaf(ev1, wvj, gv1[j]);
        }
      }
    }
    // transpose via pool (wave-private slice [h*400 .. h*400+399])
    float* gvtmp = pool;
#pragma unroll 1
    for (int pass = 0; pass < 4; ++pass) {
      WSYNC();
      if (act) {
        if (qq0 == pass) {
          float4* w = (float4*)(gvtmp + (h * 25 + ii0) * 16);
#pragma unroll
          for (int jj = 0; jj < 4; ++jj)
            w[jj] = make_float4(gv0[jj * 4], gv0[jj * 4 + 1], gv0[jj * 4 + 2], gv0[jj * 4 + 3]);
        }
        if (qq0 + 2 == pass) {
          float4* w = (float4*)(gvtmp + (h * 25 + ii0) * 16);
#pragma unroll
          for (int jj = 0; jj < 4; ++jj)
            w[jj] = make_float4(gv1[jj * 4], gv1[jj * 4 + 1], gv1[jj * 4 + 2], gv1[jj * 4 + 3]);
        }
      }
      WSYNC();
      if (qg == pass) {
#pragma unroll
        for (int i = 0; i < 25; ++i) gvt[i] = gvtmp[(h * 25 + i) * 16 + dp];
      }
    }
  }
  __syncthreads();  // pool handoff: gvtmp done, loop layout begins

  // pool layout (floats): sattn  = pool + h*112 (4 quarters x 28)
  //                       sheads = pool + 896 + h*16
  //                       spart  = pool + 1024 + par*800 + h*100 + n
  //                       sqp    = pool + 2624 + h*16   (ctx + 0.25*qp)
  float* sattnH = pool + h * 112;
  float* sheadsH = pool + 896 + h * 16;
  float* spartB = pool + 1024;
  float* sqpH = pool + 2624 + h * 16;

  // ================= Pass B: Ea rows -> sE = ctx + 0.25*E ====================
  {
    float Ea0[16], Ea1[16];
#pragma unroll
    for (int j = 0; j < 16; ++j) Ea0[j] = Ea1[j] = 0.f;
#pragma unroll 2
    for (int e4 = 0; e4 < 32; ++e4) {
      float4 a0 = sTab4[r0 * 32 + (e4 ^ sw0)];
      float4 a1 = sTab4[r1 * 32 + (e4 ^ sw1)];
      float em0[4] = {a0.x, a0.y, a0.z, a0.w};
      float em1[4] = {a1.x, a1.y, a1.z, a1.w};
#pragma unroll
      for (int eo = 0; eo < 4; ++eo) {
        const int e = e4 * 4 + eo;
        const float ev0 = em0[eo], ev1 = em1[eo];
        const float* wE = &W_step[(size_t)(128 + e) * 128 + h * 16];
#pragma unroll
        for (int j = 0; j < 16; ++j) {
          float wEj = wE[j];
          Ea0[j] = fmaf(ev0, wEj, Ea0[j]);
          Ea1[j] = fmaf(ev1, wEj, Ea1[j]);
        }
      }
    }
    if (act) {
      float4* d0 = (float4*)&sE[h][r0][0];
      float4* d1 = (float4*)&sE[h][r1][0];
#pragma unroll
      for (int jj = 0; jj < 4; ++jj) {
        d0[jj] = make_float4(ctx[jj * 4 + 0] + 0.25f * Ea0[jj * 4 + 0],
                             ctx[jj * 4 + 1] + 0.25f * Ea0[jj * 4 + 1],
                             ctx[jj * 4 + 2] + 0.25f * Ea0[jj * 4 + 2],
                             ctx[jj * 4 + 3] + 0.25f * Ea0[jj * 4 + 3]);
        d1[jj] = make_float4(ctx[jj * 4 + 0] + 0.25f * Ea1[jj * 4 + 0],
                             ctx[jj * 4 + 1] + 0.25f * Ea1[jj * 4 + 1],
                             ctx[jj * 4 + 2] + 0.25f * Ea1[jj * 4 + 2],
                             ctx[jj * 4 + 3] + 0.25f * Ea1[jj * 4 + 3]);
      }
    }
    if (l == 0) {
      float4* dq = (float4*)sqpH;
#pragma unroll
      for (int jj = 0; jj < 4; ++jj) {
        float4 w = *(const float4*)&ws[16384 + h * 16 + jj * 4];
        dq[jj] = make_float4(ctx[jj * 4 + 0] + 0.25f * w.x,
                             ctx[jj * 4 + 1] + 0.25f * w.y,
                             ctx[jj * 4 + 2] + 0.25f * w.z,
                             ctx[jj * 4 + 3] + 0.25f * w.w);
      }
    }
  }

  // ================= Pass C2: gk rows (loop-resident registers) ==============
  float gk0[16], gk1[16];
#pragma unroll
  for (int j = 0; j < 16; ++j) gk0[j] = gk1[j] = 0.f;
#pragma unroll 2
  for (int e4 = 0; e4 < 32; ++e4) {
    float4 a0 = sTab4[r0 * 32 + (e4 ^ sw0)];
    float4 a1 = sTab4[r1 * 32 + (e4 ^ sw1)];
    float em0[4] = {a0.x, a0.y, a0.z, a0.w};
    float em1[4] = {a1.x, a1.y, a1.z, a1.w};
#pragma unroll
    for (int eo = 0; eo < 4; ++eo) {
      const int e = e4 * 4 + eo;
      const float ev0 = em0[eo], ev1 = em1[eo];
      const float* wk = &W_node[e * 384 + h * 16];
#pragma unroll
      for (int j = 0; j < 16; ++j) {
        float wkj = wk[j];
        gk0[j] = fmaf(ev0, wkj, gk0[j]);
        gk1[j] = fmaf(ev1, wkj, gk1[j]);
      }
    }
  }
  __syncthreads();  // ALL sTab(emb) reads done block-wide; safe to overwrite

  // ===== Pass C1: lk' rows from GLOBAL emb -> sTab becomes the lk' table =====
  // Each thread writes only its own (row, col-slice) and is the only reader.
  {
    float lkr[16];
#pragma unroll
    for (int j = 0; j < 16; ++j) lkr[j] = 0.f;
#pragma unroll 2
    for (int e4 = 0; e4 < 32; ++e4) {
      float4 a0 = embB4[r0 * 32 + e4];
      float em0[4] = {a0.x, a0.y, a0.z, a0.w};
#pragma unroll
      for (int eo = 0; eo < 4; ++eo) {
        const int e = e4 * 4 + eo;
        const float ev0 = em0[eo];
        const float* wl = &ws[e * 128 + h * 16];
#pragma unroll
        for (int j = 0; j < 16; ++j) lkr[j] = fmaf(ev0, wl[j], lkr[j]);
      }
    }
    if (act) {
#pragma unroll
      for (int jj = 0; jj < 4; ++jj)
        sTab4[r0 * 32 + ((h * 4 + jj) ^ sw0)] =
            make_float4(lkr[4 * jj], lkr[4 * jj + 1], lkr[4 * jj + 2], lkr[4 * jj + 3]);
    }
#pragma unroll
    for (int j = 0; j < 16; ++j) lkr[j] = 0.f;
#pragma unroll 2
    for (int e4 = 0; e4 < 32; ++e4) {
      float4 a1 = embB4[r1 * 32 + e4];
      float em1[4] = {a1.x, a1.y, a1.z, a1.w};
#pragma unroll
      for (int eo = 0; eo < 4; ++eo) {
        const int e = e4 * 4 + eo;
        const float ev1 = em1[eo];
        const float* wl = &ws[e * 128 + h * 16];
#pragma unroll
        for (int j = 0; j < 16; ++j) lkr[j] = fmaf(ev1, wl[j], lkr[j]);
      }
    }
    if (act) {
#pragma unroll
      for (int jj = 0; jj < 4; ++jj)
        sTab4[r1 * 32 + ((h * 4 + jj) ^ sw1)] =
            make_float4(lkr[4 * jj], lkr[4 * jj + 1], lkr[4 * jj + 2], lkr[4 * jj + 3]);
    }
  }
  WSYNC();

  // ---- decode loop ----
  bool m0f = false, m1f = false;
  int last = 0;
  int par = 0;
  const size_t lpbase = (size_t)b * 10000;
  const float4* Lp0 = sTab4 + r0 * 32;
  const float4* Lp1 = sTab4 + r1 * 32;

#pragma unroll 1
  for (int t = 0; t < 100; ++t) {
    // (a,b) query (pre-folded: ctx[+F]+0.25E) + compat for my two rows
    const float* epf = (t == 0) ? sqpH : &sE[h][last][0];
    const float4* ep = (const float4*)epf;
    float c0a = 0.f, c0b = 0.f, c1a = 0.f, c1b = 0.f;
#pragma unroll
    for (int jj = 0; jj < 2; ++jj) {
      float4 v = ep[jj];
      c0a = fmaf(v.x, gk0[4 * jj + 0], c0a); c1a = fmaf(v.x, gk1[4 * jj + 0], c1a);
      c0a = fmaf(v.y, gk0[4 * jj + 1], c0a); c1a = fmaf(v.y, gk1[4 * jj + 1], c1a);
      c0a = fmaf(v.z, gk0[4 * jj + 2], c0a); c1a = fmaf(v.z, gk1[4 * jj + 2], c1a);
      c0a = fmaf(v.w, gk0[4 * jj + 3], c0a); c1a = fmaf(v.w, gk1[4 * jj + 3], c1a);
    }
#pragma unroll
    for (int jj = 2; jj < 4; ++jj) {
      float4 v = ep[jj];
      c0b = fmaf(v.x, gk0[4 * jj + 0], c0b); c1b = fmaf(v.x, gk1[4 * jj + 0], c1b);
      c0b = fmaf(v.y, gk0[4 * jj + 1], c0b); c1b = fmaf(v.y, gk1[4 * jj + 1], c1b);
      c0b = fmaf(v.z, gk0[4 * jj + 2], c0b); c1b = fmaf(v.z, gk1[4 * jj + 2], c1b);
      c0b = fmaf(v.w, gk0[4 * jj + 3], c0b); c1b = fmaf(v.w, gk1[4 * jj + 3], c1b);
    }
    float v0 = (act && !m0f) ? (c0a + c0b) : NEG_INF;
    float v1 = (act && !m1f) ? (c1a + c1b) : NEG_INF;

    // (c) in-wave softmax over 100 rows
    float mx = fmaxf(v0, v1);
#pragma unroll
    for (int off = 1; off < 64; off <<= 1) mx = fmaxf(mx, __shfl_xor(mx, off));
    float e0 = expf(v0 - mx), e1 = expf(v1 - mx);
    float s = e0 + e1;
#pragma unroll
    for (int off = 1; off < 64; off <<= 1) s += __shfl_xor(s, off);
    float a0 = e0 / s, a1 = e1 / s;

    // (d) attn -> wave-private LDS
    if (act) {
      sattnH[qq0 * 28 + ii0] = a0;
      sattnH[(qq0 + 2) * 28 + ii0] = a1;
    }
    WSYNC();

    // issue lk' loads NOW (step-invariant addresses) -> latency hides under
    // the heads phase; values used in (f).
    float4 L00 = Lp0[(h * 4 + 0) ^ sw0];
    float4 L01 = Lp0[(h * 4 + 1) ^ sw0];
    float4 L02 = Lp0[(h * 4 + 2) ^ sw0];
    float4 L03 = Lp0[(h * 4 + 3) ^ sw0];
    float4 L10 = Lp1[(h * 4 + 0) ^ sw1];
    float4 L11 = Lp1[(h * 4 + 1) ^ sw1];
    float4 L12 = Lp1[(h * 4 + 2) ^ sw1];
    float4 L13 = Lp1[(h * 4 + 3) ^ sw1];

    // (e) heads: lane (dp,qg) accumulates its 25 rows
    {
      const float* ap = sattnH + qg * 28;
      float ha = 0.f, hb = 0.f;
#pragma unroll
      for (int ii = 0; ii < 6; ++ii) {
        float4 v = ((const float4*)ap)[ii];
        ha = fmaf(v.x, gvt[4 * ii + 0], ha);
        hb = fmaf(v.y, gvt[4 * ii + 1], hb);
        ha = fmaf(v.z, gvt[4 * ii + 2], ha);
        hb = fmaf(v.w, gvt[4 * ii + 3], hb);
      }
      ha = fmaf(ap[24], gvt[24], ha);
      float hacc = ha + hb;
      hacc += __shfl_xor(hacc, 16);
      hacc += __shfl_xor(hacc, 32);
      if (l < 16) sheadsH[l] = hacc;
    }
    WSYNC();

    // (f) logits partial for my rows over this wave's 16 d
    float p0a = 0.f, p0b = 0.f, p1a = 0.f, p1b = 0.f;
    {
      float4 v = *(const float4*)&sheadsH[0];
      p0a = fmaf(v.x, L00.x, p0a); p1a = fmaf(v.x, L10.x, p1a);
      p0a = fmaf(v.y, L00.y, p0a); p1a = fmaf(v.y, L10.y, p1a);
      p0a = fmaf(v.z, L00.z, p0a); p1a = fmaf(v.z, L10.z, p1a);
      p0a = fmaf(v.w, L00.w, p0a); p1a = fmaf(v.w, L10.w, p1a);
    }
    {
      float4 v = *(const float4*)&sheadsH[4];
      p0a = fmaf(v.x, L01.x, p0a); p1a = fmaf(v.x, L11.x, p1a);
      p0a = fmaf(v.y, L01.y, p0a); p1a = fmaf(v.y, L11.y, p1a);
      p0a = fmaf(v.z, L01.z, p0a); p1a = fmaf(v.z, L11.z, p1a);
      p0a = fmaf(v.w, L01.w, p0a); p1a = fmaf(v.w, L11.w, p1a);
    }
    {
      float4 v = *(const float4*)&sheadsH[8];
      p0b = fmaf(v.x, L02.x, p0b); p1b = fmaf(v.x, L12.x, p1b);
      p0b = fmaf(v.y, L02.y, p0b); p1b = fmaf(v.y, L12.y, p1b);
      p0b = fmaf(v.z, L02.z, p0b); p1b = fmaf(v.z, L12.z, p1b);
      p0b = fmaf(v.w, L02.w, p0b); p1b = fmaf(v.w, L12.w, p1b);
    }
    {
      float4 v = *(const float4*)&sheadsH[12];
      p0b = fmaf(v.x, L03.x, p0b); p1b = fmaf(v.x, L13.x, p1b);
      p0b = fmaf(v.y, L03.y, p0b); p1b = fmaf(v.y, L13.y, p1b);
      p0b = fmaf(v.z, L03.z, p0b); p1b = fmaf(v.z, L13.z, p1b);
      p0b = fmaf(v.w, L03.w, p0b); p1b = fmaf(v.w, L13.w, p1b);
    }
    if (act) {
      spartB[par * 800 + h * 100 + r0] = p0a + p0b;
      spartB[par * 800 + h * 100 + r1] = p1a + p1b;
    }
    __syncthreads();  // THE barrier

    // (g) final logits: pairwise sum of 8 wave-partials, tanh-clip, mask
    const float* sp = spartB + par * 800;
    float t00 = sp[0 * 100 + r0] + sp[1 * 100 + r0];
    float t01 = sp[2 * 100 + r0] + sp[3 * 100 + r0];
    float t02 = sp[4 * 100 + r0] + sp[5 * 100 + r0];
    float t03 = sp[6 * 100 + r0] + sp[7 * 100 + r0];
    float u00 = sp[0 * 100 + r1] + sp[1 * 100 + r1];
    float u01 = sp[2 * 100 + r1] + sp[3 * 100 + r1];
    float u02 = sp[4 * 100 + r1] + sp[5 * 100 + r1];
    float u03 = sp[6 * 100 + r1] + sp[7 * 100 + r1];
    float s0 = (t00 + t01) + (t02 + t03);
    float s1 = (u00 + u01) + (u02 + u03);
    float l0 = (act && !m0f) ? 10.0f * tanhf(s0) : NEG_INF;
    float l1 = (act && !m1f) ? 10.0f * tanhf(s1) : NEG_INF;

    // (h) argmax butterfly || direct log-sum-exp (logits <= 10: Z <= 100*e^10)
    float bv; int bi;
    if (l1 > l0) { bv = l1; bi = r1; } else { bv = l0; bi = act ? r0 : 1000; }
    float z = expf(l0) + expf(l1);
#pragma unroll
    for (int off = 1; off < 64; off <<= 1) {
      float ov = __shfl_xor(bv, off);
      int oi = __shfl_xor(bi, off);
      z += __shfl_xor(z, off);
      if (ov > bv || (ov == bv && oi < bi)) { bv = ov; bi = oi; }
    }
    const int sel = bi;  // identical in every lane
    float lsum = logf(z);

    // (i) outputs (wave 0 only)
    if (h == 0) {
      if (l == 0) out_pi[b * 100 + t] = (float)sel;
      if (act) {
        out_logp[lpbase + (size_t)t * 100 + r0] = l0 - lsum;
        out_logp[lpbase + (size_t)t * 100 + r1] = l1 - lsum;
      }
    }

    // (j) t==0: fold F = 0.25*emb[first]@W_step_top into ALL sE rows + sqp done
    if (t == 0) {
      const float* erow = embB + (size_t)sel * 128;  // global, L2-hot
      float fa = 0.f;
      for (int i = 0; i < 32; ++i) {
        int e = qg * 32 + i;
        fa = fmaf(erow[e], W_step[(size_t)e * 128 + h * 16 + dp], fa);
      }
      fa += __shfl_xor(fa, 16);
      fa += __shfl_xor(fa, 32);
      if (l < 16) sbase[h][l] = 0.25f * fa;
      WSYNC();
      if (act) {
        float4* p0 = (float4*)&sE[h][r0][0];
        float4* p1 = (float4*)&sE[h][r1][0];
#pragma unroll
        for (int jj = 0; jj < 4; ++jj) {
          float4 f = *(const float4*)&sbase[h][jj * 4];
          float4 c0 = p0[jj], c1 = p1[jj];
          c0.x += f.x; c0.y += f.y; c0.z += f.z; c0.w += f.w;
          c1.x += f.x; c1.y += f.y; c1.z += f.z; c1.w += f.w;
          p0[jj] = c0; p1[jj] = c1;
        }
      }
      WSYNC();
    }

    // (k) mask update + carry
    m0f = m0f || (act && sel == r0);
    m1f = m1f || (act && sel == r1);
    last = sel;
    par ^= 1;
  }
}

extern "C" void kernel_launch(void* const* d_in, const int* in_sizes, int n_in,
                              void* d_out, int out_size, void* d_ws, size_t ws_size,
                              hipStream_t stream) {
  const float* emb     = (const float*)d_in[0];
  const float* W_node  = (const float*)d_in[1];
  const float* W_fixed = (const float*)d_in[2];
  const float* W_step  = (const float*)d_in[3];
  const float* W_out   = (const float*)d_in[4];
  const float* W_ph    = (const float*)d_in[5];
  float* ws  = (float*)d_ws;
  float* out = (float*)d_out;

  hipLaunchKernelGGL(pre_kernel, dim3(65), dim3(128), 0, stream,
                     W_node, W_out, W_step, W_ph, ws);
  hipLaunchKernelGGL(decode_kernel, dim3(2048), dim3(512), 0, stream,
                     emb, W_node, W_fixed, W_step, ws, out, out + 20480000);
}